// Round 5
// baseline (174.955 us; speedup 1.0000x reference)
//
#include <hip/hip_runtime.h>

typedef __attribute__((ext_vector_type(8))) short short8;
typedef __attribute__((ext_vector_type(4))) short short4v;
typedef __attribute__((ext_vector_type(4))) float floatx4;
typedef __attribute__((ext_vector_type(2))) float floatx2;  // native vec: ok for NT builtins

// fp32 -> bf16 round-to-nearest-even (inputs finite)
static __device__ __forceinline__ unsigned short f2bf(float f) {
    union { float f; unsigned int u; } v; v.f = f;
    unsigned int u = v.u;
    return (unsigned short)((u + 0x7FFFu + ((u >> 16) & 1u)) >> 16);
}
static __device__ __forceinline__ float bf2f(short x) {
    return __uint_as_float(((unsigned int)(unsigned short)x) << 16);
}

// Phase 1: Y[n] = [x@W1_top + b1 | x@W1_bot], bf16, Y in workspace (edge wins
// ~15µs from Y off d_in[0] — r1). r2: coalesced full-line Y stores via
// LDS-transpose epilogue (write-allocate fix, −5.4µs). r5: (a) NT-X reverted
// (r4: +7µs — X stays L3-warm across iterations now that we don't clobber it;
// nt reads forfeit that); (b) cvt_wt kernel FOLDED into staging — each block
// converts+transposes W1 (128KB, L2-resident) directly into swizzled sW.
// Removes one kernel + launch gap + the wt round-trip.
// Logical layout check (≡ old cvt∘stage composition):
//   W1[kg][n] -> sW row r=(kg>=128?128:0)+n, col k=kg&127,
//   16B-slot s=k>>3 stored at slot (s^r)&15, elem k&7.
// MFMA read uses slot ((ks*4+lq)^l15)&15 with l15=r&15 -> consistent.
__global__ __launch_bounds__(512, 4) void node_gemm_kernel(
    const float* x,                            // in: X fp32 [N,128]
    unsigned short* y,                         // out: Y bf16 [N,256]
    const float* __restrict__ w1,              // [256,128] fp32 (raw W1)
    const float* __restrict__ b1, int N)
{
    __shared__ unsigned short sW[256 * 128];   // 64KB, slot-swizzled

    const int tid = threadIdx.x;
    const int lane = tid & 63, wave = tid >> 6;
    const int l15 = lane & 15, lq = lane >> 4;

    // Stage W1 -> sW: convert fp32->bf16, transpose, XOR-swizzle slots.
#pragma unroll
    for (int i = 0; i < 16; i++) {
        int u = tid + i * 512;                 // 0..8191 float4-units of W1
        int kg = u >> 5;                       // W1 row 0..255
        int n4 = (u & 31) * 4;                 // W1 col base 0,4,..,124
        float4 f = *(const float4*)&w1[kg * 128 + n4];
        const int rbase = ((kg >> 7) << 7) + n4;  // (kg<128?0:128)+n4
        const int k = kg & 127;
        const int s = k >> 3, e = k & 7;
        sW[(rbase    ) * 128 + ((s ^ (rbase    )) & 15) * 8 + e] = f2bf(f.x);
        sW[(rbase + 1) * 128 + ((s ^ (rbase + 1)) & 15) * 8 + e] = f2bf(f.y);
        sW[(rbase + 2) * 128 + ((s ^ (rbase + 2)) & 15) * 8 + e] = f2bf(f.z);
        sW[(rbase + 3) * 128 + ((s ^ (rbase + 3)) & 15) * 8 + e] = f2bf(f.w);
    }
    __syncthreads();

    const int nr = blockIdx.x * 128 + wave * 16 + l15;
    const int nc = (nr < N) ? nr : (N - 1);
    const float* xrow = x + (size_t)nc * 128;

    floatx4 acc[16];
#pragma unroll
    for (int mt = 0; mt < 16; mt++) acc[mt] = (floatx4){0.f, 0.f, 0.f, 0.f};

#pragma unroll
    for (int kh = 0; kh < 2; kh++) {           // two k-halves of 64
        float4 xf[4];
#pragma unroll
        for (int q = 0; q < 4; q++)            // 4 loads in flight
            xf[q] = *(const float4*)(xrow + kh * 64 + (q >> 1) * 32 + lq * 8
                                     + (q & 1) * 4);
        short8 bf[2];
#pragma unroll
        for (int t = 0; t < 2; t++) {
            bf[t][0] = (short)f2bf(xf[2 * t].x);
            bf[t][1] = (short)f2bf(xf[2 * t].y);
            bf[t][2] = (short)f2bf(xf[2 * t].z);
            bf[t][3] = (short)f2bf(xf[2 * t].w);
            bf[t][4] = (short)f2bf(xf[2 * t + 1].x);
            bf[t][5] = (short)f2bf(xf[2 * t + 1].y);
            bf[t][6] = (short)f2bf(xf[2 * t + 1].z);
            bf[t][7] = (short)f2bf(xf[2 * t + 1].w);
        }
#pragma unroll
        for (int t = 0; t < 2; t++) {
            const int ks = kh * 2 + t;
#pragma unroll
            for (int mt = 0; mt < 16; mt++) {
                const short8 af = *(const short8*)
                    &sW[(mt * 16 + l15) * 128 + (((ks * 4 + lq) ^ l15) & 15) * 8];
                acc[mt] = __builtin_amdgcn_mfma_f32_16x16x32_bf16(af, bf[t],
                                                                  acc[mt], 0, 0, 0);
            }
        }
    }

    // --- epilogue: LDS transpose for full-line coalesced Y stores ---
    __syncthreads();                           // all W reads of sW complete
    {
        const int lrow = wave * 16 + l15;      // local row 0..127
#pragma unroll
        for (int mt = 0; mt < 16; mt++) {
            const int oc = mt * 16 + lq * 4;   // out-col base (C row = lq*4+i)
            float4 bb = (mt < 8) ? *(const float4*)&b1[oc]
                                 : (float4){0.f, 0.f, 0.f, 0.f};
            short4v pk;
            pk[0] = (short)f2bf(acc[mt][0] + bb.x);
            pk[1] = (short)f2bf(acc[mt][1] + bb.y);
            pk[2] = (short)f2bf(acc[mt][2] + bb.z);
            pk[3] = (short)f2bf(acc[mt][3] + bb.w);
            const int s = mt * 2 + (lq >> 1);  // 16B slot 0..31 (8B half: lq&1)
            *(short4v*)&sW[lrow * 256 + ((s ^ l15) * 8) + (lq & 1) * 4] = pk;
        }
    }
    __syncthreads();                           // block-wide transpose handoff
    {
        const int rbase = blockIdx.x * 128;
#pragma unroll
        for (int i = 0; i < 8; i++) {          // 512 thr x 8 x 16B = 64KB
            const int u = tid + i * 512;       // 16B unit 0..4095
            const int row = u >> 5, s = u & 31;
            const int grow = rbase + row;
            if (grow < N) {
                short8 v = *(const short8*)&sW[row * 256 + ((s ^ (row & 15)) * 8)];
                *(short8*)(y + (size_t)grow * 256 + s * 8) = v;  // lane-consecutive 16B
            }
        }
    }
}

// Phase 2: pure gather + reduce. out[e] = relu(Y1[s]+Y2[d]) @ W2 + b2.
// FROZEN at the demand ceiling (~6.7 TB/s L1-level; 327MB/48.5µs, stable
// across r1-r4). Single dispatch (r3: 2-way split costs +7.5µs).
__global__ __launch_bounds__(256) void edge_kernel(
    const unsigned short* __restrict__ Y,      // [N,256] bf16 (rows 512B)
    const int* __restrict__ eidx,              // [2,E] int32
    const float* __restrict__ w2,              // [128,2]
    const float* __restrict__ b2,              // [2]
    float* __restrict__ out,                   // [E,2]
    int E, int n_nodes)
{
    const int tid = threadIdx.x;
    const int lane = tid & 63, wave = tid >> 6;
    const int r = lane >> 4, cl = lane & 15;

    float w20[8], w21[8];                      // W2 slice for ch c = cl*8 + j
#pragma unroll
    for (int q = 0; q < 4; q++) {
        const float4 f = *(const float4*)&w2[cl * 16 + q * 4];
        w20[q * 2]     = f.x; w21[q * 2]     = f.y;
        w20[q * 2 + 1] = f.z; w21[q * 2 + 1] = f.w;
    }
    const float bb0 = b2[0], bb1 = b2[1];

    const long eb = (long)blockIdx.x * 256 + wave * 64;
    const char* Yb = (const char*)Y;

    int sg[4], dg[4];
    short8 buf[2][2][4];                       // [phase][src/dst][group]

#define LOAD_IDX(CH)                                                        \
    _Pragma("unroll")                                                       \
    for (int g = 0; g < 4; g++) {                                           \
        long e = eb + (CH) * 16 + g * 4 + r; if (e >= E) e = E - 1;         \
        int s = __builtin_nontemporal_load(&eidx[e]);                       \
        int d = __builtin_nontemporal_load(&eidx[(long)E + e]);             \
        sg[g] = (s < 0) ? 0 : (s >= n_nodes ? n_nodes - 1 : s);             \
        dg[g] = (d < 0) ? 0 : (d >= n_nodes ? n_nodes - 1 : d);             \
    }
#define LOAD_Y(P)                                                           \
    _Pragma("unroll")                                                       \
    for (int g = 0; g < 4; g++) {                                           \
        buf[P][0][g] = *(const short8*)(Yb + (size_t)sg[g] * 512 + cl * 16);\
        buf[P][1][g] = *(const short8*)(Yb + (size_t)dg[g] * 512 + 256      \
                                        + cl * 16);                         \
    }

    LOAD_IDX(0); LOAD_Y(0);
    LOAD_IDX(1); LOAD_Y(1);

    for (int ch = 0; ch < 4; ch++) {
        const int p = ch & 1;
        if (ch < 2) { LOAD_IDX(ch + 2); }      // idx for the refill below
#pragma unroll
        for (int g = 0; g < 4; g++) {
            float p0 = 0.f, p1 = 0.f;
#pragma unroll
            for (int j = 0; j < 8; j++) {
                float f = bf2f(buf[p][0][g][j]) + bf2f(buf[p][1][g][j]);
                f = fmaxf(f, 0.f);             // b1 folded into Y1
                p0 = fmaf(f, w20[j], p0);
                p1 = fmaf(f, w21[j], p1);
            }
#pragma unroll
            for (int m = 1; m < 16; m <<= 1) { // reduce over 16 cl-lanes
                p0 += __shfl_xor(p0, m, 64);
                p1 += __shfl_xor(p1, m, 64);
            }
            if (cl == 0) {
                const long e = eb + ch * 16 + g * 4 + r;
                if (e < E) {
                    floatx2 o;
                    o.x = p0 + bb0; o.y = p1 + bb1;
                    __builtin_nontemporal_store(o, (floatx2*)&out[e * 2]);
                }
            }
        }
        if (ch < 2) { LOAD_Y(p); }             // refill freed buffer (chunk ch+2)
    }
#undef LOAD_IDX
#undef LOAD_Y
}

extern "C" void kernel_launch(void* const* d_in, const int* in_sizes, int n_in,
                              void* d_out, int out_size, void* d_ws, size_t ws_size,
                              hipStream_t stream) {
    float*       xy   = (float*)d_in[0];       // X fp32 [N,128]
    const int*   eidx = (const int*)d_in[1];
    const float* W1   = (const float*)d_in[2];
    const float* b1   = (const float*)d_in[3];
    const float* W2   = (const float*)d_in[4];
    const float* b2   = (const float*)d_in[5];
    float* out = (float*)d_out;

    const int n_node_elems = in_sizes[0];      // N*128
    const int N = n_node_elems / 128;
    const int E = in_sizes[1] / 2;

    // Y placement: workspace if it fits (keeps d_in[0] pristine; edge gains
    // ~15µs — r1 measured); else legacy in-place over X.
    const size_t y_off   = 1u << 18;           // 256KB (alignment headroom)
    const size_t y_bytes = (size_t)N * 512;    // N rows x 256 bf16
    unsigned short* ybuf;
    if (ws_size >= y_off + y_bytes) {
        ybuf = (unsigned short*)((char*)d_ws + y_off);
    } else {
        ybuf = (unsigned short*)xy;            // fallback: in-place (aliases x)
    }

    const int nblk1 = (N + 127) / 128;
    node_gemm_kernel<<<nblk1, 512, 0, stream>>>(xy, ybuf, W1, b1, N);

    const int nblk2 = (E + 255) / 256;
    edge_kernel<<<nblk2, 256, 0, stream>>>(ybuf, eidx, W2, b2, out, E, N);
}

// Round 6
// 164.470 us; speedup vs baseline: 1.0637x; 1.0637x over previous
//
#include <hip/hip_runtime.h>

typedef __attribute__((ext_vector_type(8))) short short8;
typedef __attribute__((ext_vector_type(4))) short short4v;
typedef __attribute__((ext_vector_type(4))) float floatx4;
typedef __attribute__((ext_vector_type(2))) float floatx2;  // native vec: ok for NT builtins

// fp32 -> bf16 round-to-nearest-even (inputs finite)
static __device__ __forceinline__ unsigned short f2bf(float f) {
    union { float f; unsigned int u; } v; v.f = f;
    unsigned int u = v.u;
    return (unsigned short)((u + 0x7FFFu + ((u >> 16) & 1u)) >> 16);
}
static __device__ __forceinline__ float bf2f(short x) {
    return __uint_as_float(((unsigned int)(unsigned short)x) << 16);
}

// Phase 1: Y[n] = [x@W1_top + b1 | x@W1_bot], bf16, Y in workspace (edge wins
// ~15µs from Y off d_in[0] — r1). r2: coalesced full-line Y stores via
// LDS-transpose epilogue. r5: cvt folded into gemm, but per-element b16
// scatter = 8-way bank conflicts (1.24e7 conflict-cycles ≈ 48K cyc/CU ≈ the
// whole +20µs gemm regression — bank is f(slot,elem) only; rows are 0 mod
// 128B so a multi-row scatter can't spread banks). r6: keep the fold, stage
// via 32-row slab transpose: coalesced load -> padded sT[32][130] (bank=k%32,
// conflict-free), then per-lane short8 assembly (2-way reads = free, m136)
// and the r2-proven b128 XOR-swizzled sW write (bank-balanced).
// Layout (≡ r2 cvt∘stage): W1[kg][n] -> sW row r=(kg>=128?128:0)+n,
// col k=kg&127, 16B-slot s=k>>3 stored at slot (s^r)&15.
__global__ __launch_bounds__(512, 4) void node_gemm_kernel(
    const float* x,                            // in: X fp32 [N,128]
    unsigned short* y,                         // out: Y bf16 [N,256]
    const float* __restrict__ w1,              // [256,128] fp32 (raw W1)
    const float* __restrict__ b1, int N)
{
    __shared__ unsigned short sW[256 * 128];   // 64KB, slot-swizzled
    __shared__ unsigned short sT[32 * 130];    // 8.1KB slab temp (padded)

    const int tid = threadIdx.x;
    const int lane = tid & 63, wave = tid >> 6;
    const int l15 = lane & 15, lq = lane >> 4;

    // Stage W1 -> sW, 8 slabs of 32 W1-rows each.
    for (int slab = 0; slab < 8; slab++) {
        const int kg0 = slab * 32;
#pragma unroll
        for (int i = 0; i < 8; i++) {          // coalesced: 32x128 fp32
            int idx = tid + i * 512;           // 0..4095
            int k = idx >> 7, n = idx & 127;
            sT[k * 130 + n] = f2bf(w1[(kg0 + k) * 128 + n]);
        }
        __syncthreads();
        {                                      // 512 tasks: (n 0..127, sl 0..3)
            const int n = tid & 127, sl = tid >> 7;
            const int r = ((kg0 >> 7) << 7) + n;      // (kg0<128?0:128)+n
            const int s = ((kg0 & 127) >> 3) + sl;    // global 16B slot 0..15
            short8 v;
#pragma unroll
            for (int e = 0; e < 8; e++)
                v[e] = sT[(sl * 8 + e) * 130 + n];
            *(short8*)&sW[r * 128 + ((s ^ r) & 15) * 8] = v;
        }
        __syncthreads();
    }

    const int nr = blockIdx.x * 128 + wave * 16 + l15;
    const int nc = (nr < N) ? nr : (N - 1);
    const float* xrow = x + (size_t)nc * 128;

    floatx4 acc[16];
#pragma unroll
    for (int mt = 0; mt < 16; mt++) acc[mt] = (floatx4){0.f, 0.f, 0.f, 0.f};

#pragma unroll
    for (int kh = 0; kh < 2; kh++) {           // two k-halves of 64
        float4 xf[4];
#pragma unroll
        for (int q = 0; q < 4; q++)            // 4 loads in flight
            xf[q] = *(const float4*)(xrow + kh * 64 + (q >> 1) * 32 + lq * 8
                                     + (q & 1) * 4);
        short8 bf[2];
#pragma unroll
        for (int t = 0; t < 2; t++) {
            bf[t][0] = (short)f2bf(xf[2 * t].x);
            bf[t][1] = (short)f2bf(xf[2 * t].y);
            bf[t][2] = (short)f2bf(xf[2 * t].z);
            bf[t][3] = (short)f2bf(xf[2 * t].w);
            bf[t][4] = (short)f2bf(xf[2 * t + 1].x);
            bf[t][5] = (short)f2bf(xf[2 * t + 1].y);
            bf[t][6] = (short)f2bf(xf[2 * t + 1].z);
            bf[t][7] = (short)f2bf(xf[2 * t + 1].w);
        }
#pragma unroll
        for (int t = 0; t < 2; t++) {
            const int ks = kh * 2 + t;
#pragma unroll
            for (int mt = 0; mt < 16; mt++) {
                const short8 af = *(const short8*)
                    &sW[(mt * 16 + l15) * 128 + (((ks * 4 + lq) ^ l15) & 15) * 8];
                acc[mt] = __builtin_amdgcn_mfma_f32_16x16x32_bf16(af, bf[t],
                                                                  acc[mt], 0, 0, 0);
            }
        }
    }

    // --- epilogue: LDS transpose for full-line coalesced Y stores ---
    __syncthreads();                           // all W reads of sW complete
    {
        const int lrow = wave * 16 + l15;      // local row 0..127
#pragma unroll
        for (int mt = 0; mt < 16; mt++) {
            const int oc = mt * 16 + lq * 4;   // out-col base (C row = lq*4+i)
            float4 bb = (mt < 8) ? *(const float4*)&b1[oc]
                                 : (float4){0.f, 0.f, 0.f, 0.f};
            short4v pk;
            pk[0] = (short)f2bf(acc[mt][0] + bb.x);
            pk[1] = (short)f2bf(acc[mt][1] + bb.y);
            pk[2] = (short)f2bf(acc[mt][2] + bb.z);
            pk[3] = (short)f2bf(acc[mt][3] + bb.w);
            const int s = mt * 2 + (lq >> 1);  // 16B slot 0..31 (8B half: lq&1)
            *(short4v*)&sW[lrow * 256 + ((s ^ l15) * 8) + (lq & 1) * 4] = pk;
        }
    }
    __syncthreads();                           // block-wide transpose handoff
    {
        const int rbase = blockIdx.x * 128;
#pragma unroll
        for (int i = 0; i < 8; i++) {          // 512 thr x 8 x 16B = 64KB
            const int u = tid + i * 512;       // 16B unit 0..4095
            const int row = u >> 5, s = u & 31;
            const int grow = rbase + row;
            if (grow < N) {
                short8 v = *(const short8*)&sW[row * 256 + ((s ^ (row & 15)) * 8)];
                *(short8*)(y + (size_t)grow * 256 + s * 8) = v;  // lane-consecutive 16B
            }
        }
    }
}

// Phase 2: pure gather + reduce. out[e] = relu(Y1[s]+Y2[d]) @ W2 + b2.
// FROZEN at the demand ceiling (~6.7 TB/s L1-level; 327MB/48.5µs, stable
// across r1-r5). Single dispatch (r3: 2-way split costs +7.5µs).
__global__ __launch_bounds__(256) void edge_kernel(
    const unsigned short* __restrict__ Y,      // [N,256] bf16 (rows 512B)
    const int* __restrict__ eidx,              // [2,E] int32
    const float* __restrict__ w2,              // [128,2]
    const float* __restrict__ b2,              // [2]
    float* __restrict__ out,                   // [E,2]
    int E, int n_nodes)
{
    const int tid = threadIdx.x;
    const int lane = tid & 63, wave = tid >> 6;
    const int r = lane >> 4, cl = lane & 15;

    float w20[8], w21[8];                      // W2 slice for ch c = cl*8 + j
#pragma unroll
    for (int q = 0; q < 4; q++) {
        const float4 f = *(const float4*)&w2[cl * 16 + q * 4];
        w20[q * 2]     = f.x; w21[q * 2]     = f.y;
        w20[q * 2 + 1] = f.z; w21[q * 2 + 1] = f.w;
    }
    const float bb0 = b2[0], bb1 = b2[1];

    const long eb = (long)blockIdx.x * 256 + wave * 64;
    const char* Yb = (const char*)Y;

    int sg[4], dg[4];
    short8 buf[2][2][4];                       // [phase][src/dst][group]

#define LOAD_IDX(CH)                                                        \
    _Pragma("unroll")                                                       \
    for (int g = 0; g < 4; g++) {                                           \
        long e = eb + (CH) * 16 + g * 4 + r; if (e >= E) e = E - 1;         \
        int s = __builtin_nontemporal_load(&eidx[e]);                       \
        int d = __builtin_nontemporal_load(&eidx[(long)E + e]);             \
        sg[g] = (s < 0) ? 0 : (s >= n_nodes ? n_nodes - 1 : s);             \
        dg[g] = (d < 0) ? 0 : (d >= n_nodes ? n_nodes - 1 : d);             \
    }
#define LOAD_Y(P)                                                           \
    _Pragma("unroll")                                                       \
    for (int g = 0; g < 4; g++) {                                           \
        buf[P][0][g] = *(const short8*)(Yb + (size_t)sg[g] * 512 + cl * 16);\
        buf[P][1][g] = *(const short8*)(Yb + (size_t)dg[g] * 512 + 256      \
                                        + cl * 16);                         \
    }

    LOAD_IDX(0); LOAD_Y(0);
    LOAD_IDX(1); LOAD_Y(1);

    for (int ch = 0; ch < 4; ch++) {
        const int p = ch & 1;
        if (ch < 2) { LOAD_IDX(ch + 2); }      // idx for the refill below
#pragma unroll
        for (int g = 0; g < 4; g++) {
            float p0 = 0.f, p1 = 0.f;
#pragma unroll
            for (int j = 0; j < 8; j++) {
                float f = bf2f(buf[p][0][g][j]) + bf2f(buf[p][1][g][j]);
                f = fmaxf(f, 0.f);             // b1 folded into Y1
                p0 = fmaf(f, w20[j], p0);
                p1 = fmaf(f, w21[j], p1);
            }
#pragma unroll
            for (int m = 1; m < 16; m <<= 1) { // reduce over 16 cl-lanes
                p0 += __shfl_xor(p0, m, 64);
                p1 += __shfl_xor(p1, m, 64);
            }
            if (cl == 0) {
                const long e = eb + ch * 16 + g * 4 + r;
                if (e < E) {
                    floatx2 o;
                    o.x = p0 + bb0; o.y = p1 + bb1;
                    __builtin_nontemporal_store(o, (floatx2*)&out[e * 2]);
                }
            }
        }
        if (ch < 2) { LOAD_Y(p); }             // refill freed buffer (chunk ch+2)
    }
#undef LOAD_IDX
#undef LOAD_Y
}

extern "C" void kernel_launch(void* const* d_in, const int* in_sizes, int n_in,
                              void* d_out, int out_size, void* d_ws, size_t ws_size,
                              hipStream_t stream) {
    float*       xy   = (float*)d_in[0];       // X fp32 [N,128]
    const int*   eidx = (const int*)d_in[1];
    const float* W1   = (const float*)d_in[2];
    const float* b1   = (const float*)d_in[3];
    const float* W2   = (const float*)d_in[4];
    const float* b2   = (const float*)d_in[5];
    float* out = (float*)d_out;

    const int n_node_elems = in_sizes[0];      // N*128
    const int N = n_node_elems / 128;
    const int E = in_sizes[1] / 2;

    // Y placement: workspace if it fits (keeps d_in[0] pristine; edge gains
    // ~15µs — r1 measured); else legacy in-place over X.
    const size_t y_off   = 1u << 18;           // 256KB (alignment headroom)
    const size_t y_bytes = (size_t)N * 512;    // N rows x 256 bf16
    unsigned short* ybuf;
    if (ws_size >= y_off + y_bytes) {
        ybuf = (unsigned short*)((char*)d_ws + y_off);
    } else {
        ybuf = (unsigned short*)xy;            // fallback: in-place (aliases x)
    }

    const int nblk1 = (N + 127) / 128;
    node_gemm_kernel<<<nblk1, 512, 0, stream>>>(xy, ybuf, W1, b1, N);

    const int nblk2 = (E + 255) / 256;
    edge_kernel<<<nblk2, 256, 0, stream>>>(ybuf, eidx, W2, b2, out, E, N);
}

// Round 7
// 158.104 us; speedup vs baseline: 1.1066x; 1.0403x over previous
//
#include <hip/hip_runtime.h>

typedef __attribute__((ext_vector_type(8))) short short8;
typedef __attribute__((ext_vector_type(4))) short short4v;
typedef __attribute__((ext_vector_type(4))) float floatx4;
typedef __attribute__((ext_vector_type(2))) float floatx2;  // native vec: ok for NT builtins

// fp32 -> bf16 round-to-nearest-even (inputs finite)
static __device__ __forceinline__ unsigned short f2bf(float f) {
    union { float f; unsigned int u; } v; v.f = f;
    unsigned int u = v.u;
    return (unsigned short)((u + 0x7FFFu + ((u >> 16) & 1u)) >> 16);
}
static __device__ __forceinline__ float bf2f(short x) {
    return __uint_as_float(((unsigned int)(unsigned short)x) << 16);
}

// W1 [256,128] fp32 -> WT [256,128] bf16:
//   n' <  128: WT[n'][k] = W1[k][n']        (Y1 cols, k = top half)
//   n' >= 128: WT[n'][k] = W1[128+k][n'-128] (Y2 cols, k = bottom half)
// Also serves as the iteration's first kernel: absorbs the DVFS/cold ramp
// (r6: without it, the first gemm dispatch ate a 138µs cold outlier).
__global__ void cvt_wt_kernel(const float* __restrict__ w1,
                              unsigned short* __restrict__ wt) {
    __shared__ unsigned short sT[32 * 130];
    const int b = blockIdx.x;            // 0..7 -> W1 k-rows [b*32, b*32+32)
    const int kg0 = b * 32;
    const int h = (kg0 >= 128) ? 1 : 0;
    const int kk0 = kg0 & 127;
    const int tid = threadIdx.x;
#pragma unroll
    for (int i = 0; i < 16; i++) {       // load 32x128, coalesced in n
        int idx = tid + i * 256;
        int k = idx >> 7, n = idx & 127;
        sT[k * 130 + n] = f2bf(w1[(kg0 + k) * 128 + n]);
    }
    __syncthreads();
#pragma unroll
    for (int i = 0; i < 16; i++) {       // store, coalesced in k
        int idx = tid + i * 256;
        int n = idx >> 5, k = idx & 31;
        wt[(h * 128 + n) * 128 + kk0 + k] = sT[k * 130 + n];
    }
}

// Phase 1: Y[n] = [x@W1_top + b1 | x@W1_bot], bf16, Y in workspace (edge wins
// ~15µs from Y off d_in[0] — r1). r2: coalesced full-line Y stores via
// LDS-transpose epilogue (write-allocate fix). r4 NT-X: +7µs, reverted.
// r5/r6 cvt-fold: conflicted scatter +20µs, slab fix still ≈ +8µs vs the
// separate-cvt form (in-kernel W1 restage > cvt kernel + launch) — reverted.
// This is the r2-exact best-measured configuration (157.7µs).
__global__ __launch_bounds__(512, 4) void node_gemm_kernel(
    const float* x,                            // in: X fp32 [N,128]
    unsigned short* y,                         // out: Y bf16 [N,256]
    const unsigned short* __restrict__ wt,     // [256,128] bf16 (pre-transposed)
    const float* __restrict__ b1, int N)
{
    __shared__ unsigned short sW[256 * 128];   // 64KB, slot-swizzled

    const int tid = threadIdx.x;
    const int lane = tid & 63, wave = tid >> 6;
    const int l15 = lane & 15, lq = lane >> 4;

    // Stage WT: 16B slot s of row r stored at slot s^(r&15).
#pragma unroll
    for (int i = 0; i < 8; i++) {
        int u = tid + i * 512;                 // 0..4095 16B-units
        int r = u >> 4, s = u & 15;
        *(short8*)&sW[r * 128 + ((s ^ r) & 15) * 8] =
            *(const short8*)&wt[r * 128 + s * 8];
    }
    __syncthreads();

    const int nr = blockIdx.x * 128 + wave * 16 + l15;
    const int nc = (nr < N) ? nr : (N - 1);
    const float* xrow = x + (size_t)nc * 128;

    floatx4 acc[16];
#pragma unroll
    for (int mt = 0; mt < 16; mt++) acc[mt] = (floatx4){0.f, 0.f, 0.f, 0.f};

#pragma unroll
    for (int kh = 0; kh < 2; kh++) {           // two k-halves of 64
        float4 xf[4];
#pragma unroll
        for (int q = 0; q < 4; q++)            // 4 loads in flight
            xf[q] = *(const float4*)(xrow + kh * 64 + (q >> 1) * 32 + lq * 8
                                     + (q & 1) * 4);
        short8 bf[2];
#pragma unroll
        for (int t = 0; t < 2; t++) {
            bf[t][0] = (short)f2bf(xf[2 * t].x);
            bf[t][1] = (short)f2bf(xf[2 * t].y);
            bf[t][2] = (short)f2bf(xf[2 * t].z);
            bf[t][3] = (short)f2bf(xf[2 * t].w);
            bf[t][4] = (short)f2bf(xf[2 * t + 1].x);
            bf[t][5] = (short)f2bf(xf[2 * t + 1].y);
            bf[t][6] = (short)f2bf(xf[2 * t + 1].z);
            bf[t][7] = (short)f2bf(xf[2 * t + 1].w);
        }
#pragma unroll
        for (int t = 0; t < 2; t++) {
            const int ks = kh * 2 + t;
#pragma unroll
            for (int mt = 0; mt < 16; mt++) {
                const short8 af = *(const short8*)
                    &sW[(mt * 16 + l15) * 128 + (((ks * 4 + lq) ^ l15) & 15) * 8];
                acc[mt] = __builtin_amdgcn_mfma_f32_16x16x32_bf16(af, bf[t],
                                                                  acc[mt], 0, 0, 0);
            }
        }
    }

    // --- epilogue: LDS transpose for full-line coalesced Y stores ---
    __syncthreads();                           // all WT reads of sW complete
    {
        const int lrow = wave * 16 + l15;      // local row 0..127
#pragma unroll
        for (int mt = 0; mt < 16; mt++) {
            const int oc = mt * 16 + lq * 4;   // out-col base (C row = lq*4+i)
            float4 bb = (mt < 8) ? *(const float4*)&b1[oc]
                                 : (float4){0.f, 0.f, 0.f, 0.f};
            short4v pk;
            pk[0] = (short)f2bf(acc[mt][0] + bb.x);
            pk[1] = (short)f2bf(acc[mt][1] + bb.y);
            pk[2] = (short)f2bf(acc[mt][2] + bb.z);
            pk[3] = (short)f2bf(acc[mt][3] + bb.w);
            const int s = mt * 2 + (lq >> 1);  // 16B slot 0..31 (8B half: lq&1)
            *(short4v*)&sW[lrow * 256 + ((s ^ l15) * 8) + (lq & 1) * 4] = pk;
        }
    }
    __syncthreads();                           // block-wide transpose handoff
    {
        const int rbase = blockIdx.x * 128;
#pragma unroll
        for (int i = 0; i < 8; i++) {          // 512 thr x 8 x 16B = 64KB
            const int u = tid + i * 512;       // 16B unit 0..4095
            const int row = u >> 5, s = u & 31;
            const int grow = rbase + row;
            if (grow < N) {
                short8 v = *(const short8*)&sW[row * 256 + ((s ^ (row & 15)) * 8)];
                *(short8*)(y + (size_t)grow * 256 + s * 8) = v;  // lane-consecutive 16B
            }
        }
    }
}

// Phase 2: pure gather + reduce. out[e] = relu(Y1[s]+Y2[d]) @ W2 + b2.
// FROZEN at the demand ceiling (~6.7 TB/s L1-level; 327MB/48.5µs, stable
// across r1-r6). Single dispatch (r3: 2-way split costs +7.5µs).
__global__ __launch_bounds__(256) void edge_kernel(
    const unsigned short* __restrict__ Y,      // [N,256] bf16 (rows 512B)
    const int* __restrict__ eidx,              // [2,E] int32
    const float* __restrict__ w2,              // [128,2]
    const float* __restrict__ b2,              // [2]
    float* __restrict__ out,                   // [E,2]
    int E, int n_nodes)
{
    const int tid = threadIdx.x;
    const int lane = tid & 63, wave = tid >> 6;
    const int r = lane >> 4, cl = lane & 15;

    float w20[8], w21[8];                      // W2 slice for ch c = cl*8 + j
#pragma unroll
    for (int q = 0; q < 4; q++) {
        const float4 f = *(const float4*)&w2[cl * 16 + q * 4];
        w20[q * 2]     = f.x; w21[q * 2]     = f.y;
        w20[q * 2 + 1] = f.z; w21[q * 2 + 1] = f.w;
    }
    const float bb0 = b2[0], bb1 = b2[1];

    const long eb = (long)blockIdx.x * 256 + wave * 64;
    const char* Yb = (const char*)Y;

    int sg[4], dg[4];
    short8 buf[2][2][4];                       // [phase][src/dst][group]

#define LOAD_IDX(CH)                                                        \
    _Pragma("unroll")                                                       \
    for (int g = 0; g < 4; g++) {                                           \
        long e = eb + (CH) * 16 + g * 4 + r; if (e >= E) e = E - 1;         \
        int s = __builtin_nontemporal_load(&eidx[e]);                       \
        int d = __builtin_nontemporal_load(&eidx[(long)E + e]);             \
        sg[g] = (s < 0) ? 0 : (s >= n_nodes ? n_nodes - 1 : s);             \
        dg[g] = (d < 0) ? 0 : (d >= n_nodes ? n_nodes - 1 : d);             \
    }
#define LOAD_Y(P)                                                           \
    _Pragma("unroll")                                                       \
    for (int g = 0; g < 4; g++) {                                           \
        buf[P][0][g] = *(const short8*)(Yb + (size_t)sg[g] * 512 + cl * 16);\
        buf[P][1][g] = *(const short8*)(Yb + (size_t)dg[g] * 512 + 256      \
                                        + cl * 16);                         \
    }

    LOAD_IDX(0); LOAD_Y(0);
    LOAD_IDX(1); LOAD_Y(1);

    for (int ch = 0; ch < 4; ch++) {
        const int p = ch & 1;
        if (ch < 2) { LOAD_IDX(ch + 2); }      // idx for the refill below
#pragma unroll
        for (int g = 0; g < 4; g++) {
            float p0 = 0.f, p1 = 0.f;
#pragma unroll
            for (int j = 0; j < 8; j++) {
                float f = bf2f(buf[p][0][g][j]) + bf2f(buf[p][1][g][j]);
                f = fmaxf(f, 0.f);             // b1 folded into Y1
                p0 = fmaf(f, w20[j], p0);
                p1 = fmaf(f, w21[j], p1);
            }
#pragma unroll
            for (int m = 1; m < 16; m <<= 1) { // reduce over 16 cl-lanes
                p0 += __shfl_xor(p0, m, 64);
                p1 += __shfl_xor(p1, m, 64);
            }
            if (cl == 0) {
                const long e = eb + ch * 16 + g * 4 + r;
                if (e < E) {
                    floatx2 o;
                    o.x = p0 + bb0; o.y = p1 + bb1;
                    __builtin_nontemporal_store(o, (floatx2*)&out[e * 2]);
                }
            }
        }
        if (ch < 2) { LOAD_Y(p); }             // refill freed buffer (chunk ch+2)
    }
#undef LOAD_IDX
#undef LOAD_Y
}

extern "C" void kernel_launch(void* const* d_in, const int* in_sizes, int n_in,
                              void* d_out, int out_size, void* d_ws, size_t ws_size,
                              hipStream_t stream) {
    float*       xy   = (float*)d_in[0];       // X fp32 [N,128]
    const int*   eidx = (const int*)d_in[1];
    const float* W1   = (const float*)d_in[2];
    const float* b1   = (const float*)d_in[3];
    const float* W2   = (const float*)d_in[4];
    const float* b2   = (const float*)d_in[5];
    float* out = (float*)d_out;

    const int n_node_elems = in_sizes[0];      // N*128
    const int N = n_node_elems / 128;
    const int E = in_sizes[1] / 2;

    unsigned short* wt = (unsigned short*)d_ws;  // 64KB at ws offset 0

    // Y placement: workspace if it fits (keeps d_in[0] pristine; edge gains
    // ~15µs — r1 measured); else legacy in-place over X.
    const size_t y_off   = 1u << 18;           // 256KB (past wt, 512B-aligned)
    const size_t y_bytes = (size_t)N * 512;    // N rows x 256 bf16
    unsigned short* ybuf;
    if (ws_size >= y_off + y_bytes) {
        ybuf = (unsigned short*)((char*)d_ws + y_off);
    } else {
        ybuf = (unsigned short*)xy;            // fallback: in-place (aliases x)
    }

    cvt_wt_kernel<<<8, 256, 0, stream>>>(W1, wt);

    const int nblk1 = (N + 127) / 128;
    node_gemm_kernel<<<nblk1, 512, 0, stream>>>(xy, ybuf, wt, b1, N);

    const int nblk2 = (E + 255) / 256;
    edge_kernel<<<nblk2, 256, 0, stream>>>(ybuf, eidx, W2, b2, out, E, N);
}

// Round 8
// 156.556 us; speedup vs baseline: 1.1175x; 1.0099x over previous
//
#include <hip/hip_runtime.h>

typedef __attribute__((ext_vector_type(8))) short short8;
typedef __attribute__((ext_vector_type(4))) short short4v;
typedef __attribute__((ext_vector_type(4))) float floatx4;
typedef __attribute__((ext_vector_type(2))) float floatx2;  // native vec: ok for NT builtins

// async global->LDS 16B copy (gfx950). LDS dest must be wave-linear:
// base + lane*16 (m104) — our staging index u = tid + i*512 satisfies this.
#define ASYNC_COPY16(gsrc, ldst)                                          \
    __builtin_amdgcn_global_load_lds(                                     \
        (const __attribute__((address_space(1))) void*)(gsrc),            \
        (__attribute__((address_space(3))) void*)(ldst), 16, 0, 0)

// fp32 -> bf16 round-to-nearest-even (inputs finite)
static __device__ __forceinline__ unsigned short f2bf(float f) {
    union { float f; unsigned int u; } v; v.f = f;
    unsigned int u = v.u;
    return (unsigned short)((u + 0x7FFFu + ((u >> 16) & 1u)) >> 16);
}
static __device__ __forceinline__ float bf2f(short x) {
    return __uint_as_float(((unsigned int)(unsigned short)x) << 16);
}

// W1 [256,128] fp32 -> wt [256,128] bf16, PRE-SWIZZLED (r8):
// logical WT[np][c] (np: out-col 0..255, c: k 0..127; top half of W1 for
// np<128, bottom for np>=128) stored at wt[np*128 + ((s^(np&15))&15)*8 + e]
// with s=c>>3, e=c&7 — i.e. exactly the sW layout node_gemm's MFMA reads.
// Staging then becomes a linear 64KB memcpy (global_load_lds-able).
// Store coalescing preserved: 32-lane groups cover aligned 64B (4 slots
// XOR-permuted within an aligned-4 group). Also absorbs the DVFS cold ramp
// (r6: without a first small kernel, gemm eats a ~138µs cold outlier).
__global__ void cvt_wt_kernel(const float* __restrict__ w1,
                              unsigned short* __restrict__ wt) {
    __shared__ unsigned short sT[32 * 130];
    const int b = blockIdx.x;            // 0..7 -> W1 k-rows [b*32, b*32+32)
    const int kg0 = b * 32;
    const int h = (kg0 >= 128) ? 1 : 0;
    const int kk0 = kg0 & 127;
    const int tid = threadIdx.x;
#pragma unroll
    for (int i = 0; i < 16; i++) {       // load 32x128, coalesced in n
        int idx = tid + i * 256;
        int k = idx >> 7, n = idx & 127;
        sT[k * 130 + n] = f2bf(w1[(kg0 + k) * 128 + n]);
    }
    __syncthreads();
#pragma unroll
    for (int i = 0; i < 16; i++) {       // store, coalesced in k
        int idx = tid + i * 256;
        int n = idx >> 5, k = idx & 31;
        const int np = h * 128 + n;      // WT row (out-col)
        const int c  = kk0 + k;          // logical k-col
        const int s  = c >> 3, e = c & 7;
        wt[np * 128 + ((s ^ (np & 15)) & 15) * 8 + e] = sT[k * 130 + n];
    }
}

// Phase 1: Y[n] = [x@W1_top + b1 | x@W1_bot], bf16, Y in workspace (edge wins
// ~15µs from Y off d_in[0] — r1). r2: coalesced full-line Y stores via
// LDS-transpose epilogue (write-allocate fix). r8 (this round): merge the two
// serial L2 round-trips — (a) wt pre-swizzled, staged as a linear 64KB copy
// via global_load_lds (no VGPR round-trip, fire-and-forget); (b) all 8 X
// float4 loads issued BEFORE the barrier, so X latency hides under the
// staging drain (one vmcnt(0) covers both). MFMA + epilogue unchanged.
__global__ __launch_bounds__(512, 4) void node_gemm_kernel(
    const float* x,                            // in: X fp32 [N,128]
    unsigned short* y,                         // out: Y bf16 [N,256]
    const unsigned short* __restrict__ wt,     // [256,128] bf16 pre-swizzled
    const float* __restrict__ b1, int N)
{
    __shared__ unsigned short sW[256 * 128];   // 64KB, slot-swizzled

    const int tid = threadIdx.x;
    const int lane = tid & 63, wave = tid >> 6;
    const int l15 = lane & 15, lq = lane >> 4;

    // Stage wt -> sW: linear 64KB async copy (layout already swizzled).
#pragma unroll
    for (int i = 0; i < 8; i++) {
        const int u = tid + i * 512;           // 16B unit 0..4095, lane-linear
        ASYNC_COPY16(wt + u * 8, &sW[u * 8]);
    }

    // Issue X row loads now — latency hides under the staging drain.
    const int nr = blockIdx.x * 128 + wave * 16 + l15;
    const int nc = (nr < N) ? nr : (N - 1);
    const float* xrow = x + (size_t)nc * 128;
    float4 xf[8];
#pragma unroll
    for (int kh = 0; kh < 2; kh++)
#pragma unroll
        for (int q = 0; q < 4; q++)
            xf[kh * 4 + q] = *(const float4*)(xrow + kh * 64 + (q >> 1) * 32
                                              + lq * 8 + (q & 1) * 4);

    __syncthreads();                           // drains staging + X loads

    floatx4 acc[16];
#pragma unroll
    for (int mt = 0; mt < 16; mt++) acc[mt] = (floatx4){0.f, 0.f, 0.f, 0.f};

#pragma unroll
    for (int kh = 0; kh < 2; kh++) {           // two k-halves of 64
        short8 bf[2];
#pragma unroll
        for (int t = 0; t < 2; t++) {
            const float4 a = xf[kh * 4 + 2 * t];
            const float4 b = xf[kh * 4 + 2 * t + 1];
            bf[t][0] = (short)f2bf(a.x);
            bf[t][1] = (short)f2bf(a.y);
            bf[t][2] = (short)f2bf(a.z);
            bf[t][3] = (short)f2bf(a.w);
            bf[t][4] = (short)f2bf(b.x);
            bf[t][5] = (short)f2bf(b.y);
            bf[t][6] = (short)f2bf(b.z);
            bf[t][7] = (short)f2bf(b.w);
        }
#pragma unroll
        for (int t = 0; t < 2; t++) {
            const int ks = kh * 2 + t;
#pragma unroll
            for (int mt = 0; mt < 16; mt++) {
                const short8 af = *(const short8*)
                    &sW[(mt * 16 + l15) * 128 + (((ks * 4 + lq) ^ l15) & 15) * 8];
                acc[mt] = __builtin_amdgcn_mfma_f32_16x16x32_bf16(af, bf[t],
                                                                  acc[mt], 0, 0, 0);
            }
        }
    }

    // --- epilogue: LDS transpose for full-line coalesced Y stores ---
    __syncthreads();                           // all WT reads of sW complete
    {
        const int lrow = wave * 16 + l15;      // local row 0..127
#pragma unroll
        for (int mt = 0; mt < 16; mt++) {
            const int oc = mt * 16 + lq * 4;   // out-col base (C row = lq*4+i)
            float4 bb = (mt < 8) ? *(const float4*)&b1[oc]
                                 : (float4){0.f, 0.f, 0.f, 0.f};
            short4v pk;
            pk[0] = (short)f2bf(acc[mt][0] + bb.x);
            pk[1] = (short)f2bf(acc[mt][1] + bb.y);
            pk[2] = (short)f2bf(acc[mt][2] + bb.z);
            pk[3] = (short)f2bf(acc[mt][3] + bb.w);
            const int s = mt * 2 + (lq >> 1);  // 16B slot 0..31 (8B half: lq&1)
            *(short4v*)&sW[lrow * 256 + ((s ^ l15) * 8) + (lq & 1) * 4] = pk;
        }
    }
    __syncthreads();                           // block-wide transpose handoff
    {
        const int rbase = blockIdx.x * 128;
#pragma unroll
        for (int i = 0; i < 8; i++) {          // 512 thr x 8 x 16B = 64KB
            const int u = tid + i * 512;       // 16B unit 0..4095
            const int row = u >> 5, s = u & 31;
            const int grow = rbase + row;
            if (grow < N) {
                short8 v = *(const short8*)&sW[row * 256 + ((s ^ (row & 15)) * 8)];
                *(short8*)(y + (size_t)grow * 256 + s * 8) = v;  // lane-consecutive 16B
            }
        }
    }
}

// Phase 2: pure gather + reduce. out[e] = relu(Y1[s]+Y2[d]) @ W2 + b2.
// FROZEN at the demand ceiling (~6.7 TB/s L1-level; 327MB/48.5µs, stable
// across r1-r7). Single dispatch (r3: 2-way split costs +7.5µs).
__global__ __launch_bounds__(256) void edge_kernel(
    const unsigned short* __restrict__ Y,      // [N,256] bf16 (rows 512B)
    const int* __restrict__ eidx,              // [2,E] int32
    const float* __restrict__ w2,              // [128,2]
    const float* __restrict__ b2,              // [2]
    float* __restrict__ out,                   // [E,2]
    int E, int n_nodes)
{
    const int tid = threadIdx.x;
    const int lane = tid & 63, wave = tid >> 6;
    const int r = lane >> 4, cl = lane & 15;

    float w20[8], w21[8];                      // W2 slice for ch c = cl*8 + j
#pragma unroll
    for (int q = 0; q < 4; q++) {
        const float4 f = *(const float4*)&w2[cl * 16 + q * 4];
        w20[q * 2]     = f.x; w21[q * 2]     = f.y;
        w20[q * 2 + 1] = f.z; w21[q * 2 + 1] = f.w;
    }
    const float bb0 = b2[0], bb1 = b2[1];

    const long eb = (long)blockIdx.x * 256 + wave * 64;
    const char* Yb = (const char*)Y;

    int sg[4], dg[4];
    short8 buf[2][2][4];                       // [phase][src/dst][group]

#define LOAD_IDX(CH)                                                        \
    _Pragma("unroll")                                                       \
    for (int g = 0; g < 4; g++) {                                           \
        long e = eb + (CH) * 16 + g * 4 + r; if (e >= E) e = E - 1;         \
        int s = __builtin_nontemporal_load(&eidx[e]);                       \
        int d = __builtin_nontemporal_load(&eidx[(long)E + e]);             \
        sg[g] = (s < 0) ? 0 : (s >= n_nodes ? n_nodes - 1 : s);             \
        dg[g] = (d < 0) ? 0 : (d >= n_nodes ? n_nodes - 1 : d);             \
    }
#define LOAD_Y(P)                                                           \
    _Pragma("unroll")                                                       \
    for (int g = 0; g < 4; g++) {                                           \
        buf[P][0][g] = *(const short8*)(Yb + (size_t)sg[g] * 512 + cl * 16);\
        buf[P][1][g] = *(const short8*)(Yb + (size_t)dg[g] * 512 + 256      \
                                        + cl * 16);                         \
    }

    LOAD_IDX(0); LOAD_Y(0);
    LOAD_IDX(1); LOAD_Y(1);

    for (int ch = 0; ch < 4; ch++) {
        const int p = ch & 1;
        if (ch < 2) { LOAD_IDX(ch + 2); }      // idx for the refill below
#pragma unroll
        for (int g = 0; g < 4; g++) {
            float p0 = 0.f, p1 = 0.f;
#pragma unroll
            for (int j = 0; j < 8; j++) {
                float f = bf2f(buf[p][0][g][j]) + bf2f(buf[p][1][g][j]);
                f = fmaxf(f, 0.f);             // b1 folded into Y1
                p0 = fmaf(f, w20[j], p0);
                p1 = fmaf(f, w21[j], p1);
            }
#pragma unroll
            for (int m = 1; m < 16; m <<= 1) { // reduce over 16 cl-lanes
                p0 += __shfl_xor(p0, m, 64);
                p1 += __shfl_xor(p1, m, 64);
            }
            if (cl == 0) {
                const long e = eb + ch * 16 + g * 4 + r;
                if (e < E) {
                    floatx2 o;
                    o.x = p0 + bb0; o.y = p1 + bb1;
                    __builtin_nontemporal_store(o, (floatx2*)&out[e * 2]);
                }
            }
        }
        if (ch < 2) { LOAD_Y(p); }             // refill freed buffer (chunk ch+2)
    }
#undef LOAD_IDX
#undef LOAD_Y
}

extern "C" void kernel_launch(void* const* d_in, const int* in_sizes, int n_in,
                              void* d_out, int out_size, void* d_ws, size_t ws_size,
                              hipStream_t stream) {
    float*       xy   = (float*)d_in[0];       // X fp32 [N,128]
    const int*   eidx = (const int*)d_in[1];
    const float* W1   = (const float*)d_in[2];
    const float* b1   = (const float*)d_in[3];
    const float* W2   = (const float*)d_in[4];
    const float* b2   = (const float*)d_in[5];
    float* out = (float*)d_out;

    const int n_node_elems = in_sizes[0];      // N*128
    const int N = n_node_elems / 128;
    const int E = in_sizes[1] / 2;

    unsigned short* wt = (unsigned short*)d_ws;  // 64KB at ws offset 0

    // Y placement: workspace if it fits (keeps d_in[0] pristine; edge gains
    // ~15µs — r1 measured); else legacy in-place over X.
    const size_t y_off   = 1u << 18;           // 256KB (past wt, 512B-aligned)
    const size_t y_bytes = (size_t)N * 512;    // N rows x 256 bf16
    unsigned short* ybuf;
    if (ws_size >= y_off + y_bytes) {
        ybuf = (unsigned short*)((char*)d_ws + y_off);
    } else {
        ybuf = (unsigned short*)xy;            // fallback: in-place (aliases x)
    }

    cvt_wt_kernel<<<8, 256, 0, stream>>>(W1, wt);

    const int nblk1 = (N + 127) / 128;
    node_gemm_kernel<<<nblk1, 512, 0, stream>>>(xy, ybuf, wt, b1, N);

    const int nblk2 = (E + 255) / 256;
    edge_kernel<<<nblk2, 256, 0, stream>>>(ybuf, eidx, W2, b2, out, E, N);
}